// Round 1
// baseline (3813.315 us; speedup 1.0000x reference)
//
#include <hip/hip_runtime.h>
#include <cstdint>
#include <cstddef>

#define E_DIM 1024
#define D_DIM 64
#define H_DIM 16
#define F_DIM 4096
#define B_DIM 2
#define S_DIM 2048
#define M_DIM (B_DIM * S_DIM)  /* 4096 rows */
#define LN_EPS 1e-5f

// ---------------------------------------------------------------------------
// LayerNorm over last dim (E=1024). One block per row, 256 threads x 4 elems.
// ---------------------------------------------------------------------------
__global__ __launch_bounds__(256) void ln_kernel(const float* __restrict__ x,
                                                 const float* __restrict__ g,
                                                 const float* __restrict__ b,
                                                 float* __restrict__ out) {
  const int row = blockIdx.x;
  const float* xp = x + (size_t)row * E_DIM;
  const int t4 = threadIdx.x * 4;
  float4 xv = *(const float4*)(xp + t4);
  float s = xv.x + xv.y + xv.z + xv.w;
  float ss = xv.x * xv.x + xv.y * xv.y + xv.z * xv.z + xv.w * xv.w;
#pragma unroll
  for (int off = 32; off > 0; off >>= 1) {
    s += __shfl_down(s, off);
    ss += __shfl_down(ss, off);
  }
  __shared__ float red[8];
  const int wid = threadIdx.x >> 6;
  if ((threadIdx.x & 63) == 0) {
    red[wid] = s;
    red[4 + wid] = ss;
  }
  __syncthreads();
  if (threadIdx.x == 0) {
    float S = red[0] + red[1] + red[2] + red[3];
    float SS = red[4] + red[5] + red[6] + red[7];
    float mean = S * (1.0f / E_DIM);
    float var = SS * (1.0f / E_DIM) - mean * mean;
    red[0] = mean;
    red[1] = rsqrtf(var + LN_EPS);
  }
  __syncthreads();
  const float mean = red[0], rstd = red[1];
  float4 gv = *(const float4*)(g + t4);
  float4 bv = *(const float4*)(b + t4);
  float4 ov;
  ov.x = (xv.x - mean) * rstd * gv.x + bv.x;
  ov.y = (xv.y - mean) * rstd * gv.y + bv.y;
  ov.z = (xv.z - mean) * rstd * gv.z + bv.z;
  ov.w = (xv.w - mean) * rstd * gv.w + bv.w;
  *(float4*)(out + (size_t)row * E_DIM + t4) = ov;
}

// ---------------------------------------------------------------------------
// fp32 tiled GEMM: C[M,N] = A[M,K] @ B[K,N] (+bias, +residual / relu / qkv
// scatter). 128x128 tile, BK=16, 256 threads, 8x8 per thread.
// MODE 0: B is per-head [H,E,D] (col n -> head n>>6, d n&63); out scattered
//         to [H*B, S, D]; bias[n].
// MODE 1: B row-major; out = resid + acc + bias   (Wo, W2)
// MODE 2: B row-major; out = relu(acc + bias)     (W1)
// ---------------------------------------------------------------------------
template <int MODE>
__global__ __launch_bounds__(256) void gemm_kernel(
    const float* __restrict__ A, const float* __restrict__ Bw,
    const float* __restrict__ bias, const float* __restrict__ resid,
    float* __restrict__ out, int N, int K) {
  __shared__ float As[16][132];
  __shared__ float Bs[16][132];
  const int tid = threadIdx.x;
  const int tx = tid & 15, ty = tid >> 4;
  const int m0 = blockIdx.y * 128, n0 = blockIdx.x * 128;

  float acc[8][8];
#pragma unroll
  for (int i = 0; i < 8; ++i)
#pragma unroll
    for (int j = 0; j < 8; ++j) acc[i][j] = 0.f;

  for (int k0 = 0; k0 < K; k0 += 16) {
#pragma unroll
    for (int l = 0; l < 2; ++l) {
      int f = tid + l * 256;
      int r = f >> 2;
      int c4 = (f & 3) << 2;
      float4 av = *(const float4*)(A + (size_t)(m0 + r) * K + k0 + c4);
      As[c4 + 0][r] = av.x;
      As[c4 + 1][r] = av.y;
      As[c4 + 2][r] = av.z;
      As[c4 + 3][r] = av.w;
      int rb = f >> 5;
      int cb = (f & 31) << 2;
      float4 bv4;
      if (MODE == 0) {
        int n = n0 + cb;
        bv4 = *(const float4*)(Bw + (size_t)(n >> 6) * (E_DIM * D_DIM) +
                               (size_t)(k0 + rb) * D_DIM + (n & 63));
      } else {
        bv4 = *(const float4*)(Bw + (size_t)(k0 + rb) * N + n0 + cb);
      }
      *(float4*)&Bs[rb][cb] = bv4;
    }
    __syncthreads();
#pragma unroll
    for (int kk = 0; kk < 16; ++kk) {
      float4 a0 = *(const float4*)&As[kk][ty * 8];
      float4 a1 = *(const float4*)&As[kk][ty * 8 + 4];
      float4 b0 = *(const float4*)&Bs[kk][tx * 8];
      float4 b1 = *(const float4*)&Bs[kk][tx * 8 + 4];
      float a[8] = {a0.x, a0.y, a0.z, a0.w, a1.x, a1.y, a1.z, a1.w};
      float b[8] = {b0.x, b0.y, b0.z, b0.w, b1.x, b1.y, b1.z, b1.w};
#pragma unroll
      for (int i = 0; i < 8; ++i)
#pragma unroll
        for (int j = 0; j < 8; ++j) acc[i][j] = fmaf(a[i], b[j], acc[i][j]);
    }
    __syncthreads();
  }

#pragma unroll
  for (int i = 0; i < 8; ++i) {
    int r = m0 + ty * 8 + i;
#pragma unroll
    for (int j4 = 0; j4 < 8; j4 += 4) {
      int n = n0 + tx * 8 + j4;
      float4 bv4 = *(const float4*)(bias + n);
      float4 val;
      val.x = acc[i][j4 + 0] + bv4.x;
      val.y = acc[i][j4 + 1] + bv4.y;
      val.z = acc[i][j4 + 2] + bv4.z;
      val.w = acc[i][j4 + 3] + bv4.w;
      if (MODE == 1) {
        float4 rv = *(const float4*)(resid + (size_t)r * N + n);
        val.x += rv.x;
        val.y += rv.y;
        val.z += rv.z;
        val.w += rv.w;
      }
      if (MODE == 2) {
        val.x = fmaxf(val.x, 0.f);
        val.y = fmaxf(val.y, 0.f);
        val.z = fmaxf(val.z, 0.f);
        val.w = fmaxf(val.w, 0.f);
      }
      if (MODE == 0) {
        int hh = n >> 6, d = n & 63;
        int bb = r >> 11, srow = r & 2047;
        *(float4*)(out + ((size_t)(hh * B_DIM + bb) * S_DIM + srow) * D_DIM +
                   d) = val;
      } else {
        *(float4*)(out + (size_t)r * N + n) = val;
      }
    }
  }
}

// ---------------------------------------------------------------------------
// Attention (faithful quirk): for each (h,b) pair, output row s (key index):
//   logits[t] = k[s,:] . q[t,:]  (no scaling), softmax over t,
//   o[s,:] = sum_t att[s,t] * v[t,:]
// Flash-style online softmax. 1 thread = 1 row s; t-tiles of 32 staged in LDS
// (reads are wave-uniform broadcasts). q,k,v: [H*B, S, D]; o: [B, S, H, D].
// ---------------------------------------------------------------------------
__global__ __launch_bounds__(256, 1) void attn_kernel(
    const float* __restrict__ q, const float* __restrict__ k,
    const float* __restrict__ v, float* __restrict__ o) {
  const int pair = blockIdx.x >> 3;   // h*B + b
  const int stile = blockIdx.x & 7;
  const size_t base = (size_t)pair * S_DIM * D_DIM;
  const int s = stile * 256 + threadIdx.x;

  float krow[64];
  const float* kp = k + base + (size_t)s * D_DIM;
#pragma unroll
  for (int d4 = 0; d4 < 64; d4 += 4) {
    float4 t = *(const float4*)(kp + d4);
    krow[d4] = t.x;
    krow[d4 + 1] = t.y;
    krow[d4 + 2] = t.z;
    krow[d4 + 3] = t.w;
  }
  float mrun = -1e30f, lrun = 0.f;
  float oacc[64];
#pragma unroll
  for (int d = 0; d < 64; ++d) oacc[d] = 0.f;

  __shared__ float qs[32][64];
  __shared__ float vs[32][64];

  for (int t0 = 0; t0 < S_DIM; t0 += 32) {
#pragma unroll
    for (int l2 = 0; l2 < 2; ++l2) {
      int f = threadIdx.x + l2 * 256;  // float4 id 0..511
      int r = f >> 4;
      int c = (f & 15) * 4;
      *(float4*)&qs[r][c] = *(const float4*)(q + base + (size_t)(t0 + r) * D_DIM + c);
      *(float4*)&vs[r][c] = *(const float4*)(v + base + (size_t)(t0 + r) * D_DIM + c);
    }
    __syncthreads();

    float p[32];
    float pmax = -1e30f;
#pragma unroll
    for (int t = 0; t < 32; ++t) {
      float dot = 0.f;
#pragma unroll
      for (int d4 = 0; d4 < 64; d4 += 4) {
        float4 qv = *(const float4*)&qs[t][d4];
        dot = fmaf(krow[d4], qv.x, dot);
        dot = fmaf(krow[d4 + 1], qv.y, dot);
        dot = fmaf(krow[d4 + 2], qv.z, dot);
        dot = fmaf(krow[d4 + 3], qv.w, dot);
      }
      p[t] = dot;
      pmax = fmaxf(pmax, dot);
    }
    float mnew = fmaxf(mrun, pmax);
    float scale = __expf(mrun - mnew);
    lrun *= scale;
#pragma unroll
    for (int d = 0; d < 64; ++d) oacc[d] *= scale;
#pragma unroll
    for (int t = 0; t < 32; ++t) {
      float e = __expf(p[t] - mnew);
      lrun += e;
#pragma unroll
      for (int d4 = 0; d4 < 64; d4 += 4) {
        float4 vv = *(const float4*)&vs[t][d4];
        oacc[d4] = fmaf(e, vv.x, oacc[d4]);
        oacc[d4 + 1] = fmaf(e, vv.y, oacc[d4 + 1]);
        oacc[d4 + 2] = fmaf(e, vv.z, oacc[d4 + 2]);
        oacc[d4 + 3] = fmaf(e, vv.w, oacc[d4 + 3]);
      }
    }
    mrun = mnew;
    __syncthreads();
  }

  const float inv = 1.f / lrun;
  const int hh = pair >> 1, bb = pair & 1;  // pair = h*B + b, B=2
  float* op = o + ((size_t)(bb * S_DIM + s)) * (H_DIM * D_DIM) + hh * D_DIM;
#pragma unroll
  for (int d4 = 0; d4 < 64; d4 += 4) {
    float4 val;
    val.x = oacc[d4] * inv;
    val.y = oacc[d4 + 1] * inv;
    val.z = oacc[d4 + 2] * inv;
    val.w = oacc[d4 + 3] * inv;
    *(float4*)(op + d4) = val;
  }
}

// ---------------------------------------------------------------------------
extern "C" void kernel_launch(void* const* d_in, const int* in_sizes, int n_in,
                              void* d_out, int out_size, void* d_ws,
                              size_t ws_size, hipStream_t stream) {
  const float* x = (const float*)d_in[0];
  const float* Wq = (const float*)d_in[1];
  const float* bq = (const float*)d_in[2];
  const float* Wk = (const float*)d_in[3];
  const float* bk = (const float*)d_in[4];
  const float* Wv = (const float*)d_in[5];
  const float* bv = (const float*)d_in[6];
  const float* Wo = (const float*)d_in[7];
  const float* bo = (const float*)d_in[8];
  const float* ln1_g = (const float*)d_in[9];
  const float* ln1_b = (const float*)d_in[10];
  const float* ln2_g = (const float*)d_in[11];
  const float* ln2_b = (const float*)d_in[12];
  const float* W1 = (const float*)d_in[13];
  const float* b1 = (const float*)d_in[14];
  const float* W2 = (const float*)d_in[15];
  const float* b2 = (const float*)d_in[16];
  float* out = (float*)d_out;
  float* ws = (float*)d_ws;

  // workspace layout (floats). m1 aliases q..o (all dead by the time m1 is
  // written). Total需要 24M floats = 96 MB.
  float* h = ws;                    // 4M  [4096,1024]  (LN1 out, later LN2 out)
  float* q = ws + 4194304;          // 4M  [H*B, S, D]
  float* kbuf = ws + 8388608;       // 4M
  float* vbuf = ws + 12582912;      // 4M
  float* o = ws + 16777216;         // 4M  [B, S, H*D]
  float* x2 = ws + 20971520;        // 4M  [4096,1024]
  float* m1 = ws + 4194304;         // 16M [4096,4096] (aliases q,k,v,o)

  const dim3 blk(256);
  const dim3 g_n8(8, 32);    // N=1024 tiles x M=4096 tiles
  const dim3 g_n32(32, 32);  // N=4096

  ln_kernel<<<M_DIM, blk, 0, stream>>>(x, ln1_g, ln1_b, h);

  gemm_kernel<0><<<g_n8, blk, 0, stream>>>(h, Wq, bq, nullptr, q, 1024, 1024);
  gemm_kernel<0><<<g_n8, blk, 0, stream>>>(h, Wk, bk, nullptr, kbuf, 1024, 1024);
  gemm_kernel<0><<<g_n8, blk, 0, stream>>>(h, Wv, bv, nullptr, vbuf, 1024, 1024);

  attn_kernel<<<256, blk, 0, stream>>>(q, kbuf, vbuf, o);

  gemm_kernel<1><<<g_n8, blk, 0, stream>>>(o, Wo, bo, x, x2, 1024, 1024);

  ln_kernel<<<M_DIM, blk, 0, stream>>>(x2, ln2_g, ln2_b, h);

  gemm_kernel<2><<<g_n32, blk, 0, stream>>>(h, W1, b1, nullptr, m1, 4096, 1024);
  gemm_kernel<1><<<g_n8, blk, 0, stream>>>(m1, W2, b2, x2, out, 1024, 4096);
}

// Round 2
// 733.645 us; speedup vs baseline: 5.1978x; 5.1978x over previous
//
#include <hip/hip_runtime.h>
#include <cstdint>
#include <cstddef>

typedef __attribute__((ext_vector_type(8))) short short8;
typedef __attribute__((ext_vector_type(4))) float f32x4;
typedef __attribute__((ext_vector_type(4))) unsigned short ushort4v;

#define E_DIM 1024
#define D_DIM 64
#define H_DIM 16
#define F_DIM 4096
#define B_DIM 2
#define S_DIM 2048
#define M_DIM 4096
#define LN_EPS 1e-5f

__device__ __forceinline__ float bf2f(unsigned short u) {
  union { unsigned int i; float f; } v;
  v.i = ((unsigned int)u) << 16;
  return v.f;
}
__device__ __forceinline__ unsigned short f2bf(float f) {
  union { float f; unsigned int i; } v;
  v.f = f;
  unsigned int r = v.i + 0x7FFFu + ((v.i >> 16) & 1u);
  return (unsigned short)(r >> 16);
}

__device__ __forceinline__ void gload_lds16(const unsigned short* src,
                                            unsigned short* dst) {
  __builtin_amdgcn_global_load_lds(
      (const __attribute__((address_space(1))) void*)src,
      (__attribute__((address_space(3))) void*)dst, 16, 0, 0);
}

// ---------------------------------------------------------------------------
// Weight prep: transpose fp32 [R][C] -> bf16 [C][R] (hi, optional lo).
// QKV=true: input is [H][E][D] with logical (r=e, c=h*64+d).
// ---------------------------------------------------------------------------
template <bool QKV, bool LO>
__global__ __launch_bounds__(256) void transpose_w(
    const float* __restrict__ in, unsigned short* __restrict__ ohi,
    unsigned short* __restrict__ olo, int R, int C) {
  __shared__ float t[32][33];
  const int c0 = blockIdx.x * 32, r0 = blockIdx.y * 32;
  const int tid = threadIdx.x;
  {
    const int rr = tid >> 3, c4 = (tid & 7) * 4;
    size_t addr;
    if (QKV)
      addr = (size_t)(c0 >> 6) * 65536 + (size_t)(r0 + rr) * 64 +
             ((c0 & 63) + c4);
    else
      addr = (size_t)(r0 + rr) * C + (c0 + c4);
    float4 v = *(const float4*)(in + addr);
    t[rr][c4 + 0] = v.x;
    t[rr][c4 + 1] = v.y;
    t[rr][c4 + 2] = v.z;
    t[rr][c4 + 3] = v.w;
  }
  __syncthreads();
  {
    const int cc = tid >> 3, k4 = (tid & 7) * 4;
    float a = t[k4 + 0][cc], b = t[k4 + 1][cc], c = t[k4 + 2][cc],
          d = t[k4 + 3][cc];
    ushort4v hi;
    hi.x = f2bf(a); hi.y = f2bf(b); hi.z = f2bf(c); hi.w = f2bf(d);
    size_t oaddr = (size_t)(c0 + cc) * R + (r0 + k4);
    *(ushort4v*)(ohi + oaddr) = hi;
    if constexpr (LO) {
      ushort4v lo;
      lo.x = f2bf(a - bf2f(hi.x));
      lo.y = f2bf(b - bf2f(hi.y));
      lo.z = f2bf(c - bf2f(hi.z));
      lo.w = f2bf(d - bf2f(hi.w));
      *(ushort4v*)(olo + oaddr) = lo;
    }
  }
}

// ---------------------------------------------------------------------------
// LayerNorm fp32 in -> bf16 out (hi, optional lo split for fp32-accurate GEMM)
// ---------------------------------------------------------------------------
template <bool LO>
__global__ __launch_bounds__(256) void ln_kernel(
    const float* __restrict__ x, const float* __restrict__ g,
    const float* __restrict__ b, unsigned short* __restrict__ ohi,
    unsigned short* __restrict__ olo) {
  const int row = blockIdx.x;
  const float* xp = x + (size_t)row * E_DIM;
  const int t4 = threadIdx.x * 4;
  float4 xv = *(const float4*)(xp + t4);
  float s = xv.x + xv.y + xv.z + xv.w;
  float ss = xv.x * xv.x + xv.y * xv.y + xv.z * xv.z + xv.w * xv.w;
#pragma unroll
  for (int off = 32; off > 0; off >>= 1) {
    s += __shfl_down(s, off);
    ss += __shfl_down(ss, off);
  }
  __shared__ float red[8];
  const int wid = threadIdx.x >> 6;
  if ((threadIdx.x & 63) == 0) {
    red[wid] = s;
    red[4 + wid] = ss;
  }
  __syncthreads();
  if (threadIdx.x == 0) {
    float S = red[0] + red[1] + red[2] + red[3];
    float SS = red[4] + red[5] + red[6] + red[7];
    float mean = S * (1.0f / E_DIM);
    float var = SS * (1.0f / E_DIM) - mean * mean;
    red[0] = mean;
    red[1] = rsqrtf(var + LN_EPS);
  }
  __syncthreads();
  const float mean = red[0], rstd = red[1];
  float4 gv = *(const float4*)(g + t4);
  float4 bv = *(const float4*)(b + t4);
  float o0 = (xv.x - mean) * rstd * gv.x + bv.x;
  float o1 = (xv.y - mean) * rstd * gv.y + bv.y;
  float o2 = (xv.z - mean) * rstd * gv.z + bv.z;
  float o3 = (xv.w - mean) * rstd * gv.w + bv.w;
  ushort4v hi;
  hi.x = f2bf(o0); hi.y = f2bf(o1); hi.z = f2bf(o2); hi.w = f2bf(o3);
  *(ushort4v*)(ohi + (size_t)row * E_DIM + t4) = hi;
  if constexpr (LO) {
    ushort4v lo;
    lo.x = f2bf(o0 - bf2f(hi.x));
    lo.y = f2bf(o1 - bf2f(hi.y));
    lo.z = f2bf(o2 - bf2f(hi.z));
    lo.w = f2bf(o3 - bf2f(hi.w));
    *(ushort4v*)(olo + (size_t)row * E_DIM + t4) = lo;
  }
}

// ---------------------------------------------------------------------------
// MFMA GEMM: C[M,N] = A[M,K] * B^T (B stored [N][K], both bf16 rows).
// 128x128 tile, BK=64, 4 waves (each 64x64 = 4x4 of 16x16x32 MFMA).
// global_load_lds width-16 staging with XOR-swizzled LDS (byte ^= (row&7)<<4).
// SPLIT: A,B have hi+lo parts; acc += Ahi*Bhi + Ahi*Blo + Alo*Bhi.
// MODE 0: scatter hi+lo bf16 to [pair][s][d]   (Q,K proj; pair=(n>>6)*2+(m>>11))
// MODE 1: scatter hi bf16 to Vt [pair][d][s]   (V proj)
// MODE 2: fp32 out[m][n] = acc + bias[n] + resid[m][n]   (Wo, W2)
// MODE 3: bf16 out[m][n] = relu(acc + bias[n])           (W1)
// ---------------------------------------------------------------------------
template <int MODE, bool SPLIT>
__global__ __launch_bounds__(256) void mfma_gemm(
    const unsigned short* __restrict__ Ahi, const unsigned short* __restrict__ Alo,
    const unsigned short* __restrict__ Bhi, const unsigned short* __restrict__ Blo,
    const float* __restrict__ bias, const float* __restrict__ resid,
    void* __restrict__ out0, unsigned short* __restrict__ out1,
    int M, int N, int K) {
  extern __shared__ unsigned short smem[];
  unsigned short* As = smem;           // [128][64] bf16, swizzled
  unsigned short* Bs = smem + 8192;
  unsigned short* Als = smem + 16384;  // only if SPLIT
  unsigned short* Bls = smem + 24576;
  const int tid = threadIdx.x;
  const int m0 = blockIdx.y * 128, n0 = blockIdx.x * 128;
  const int lane = tid & 63, wid = tid >> 6;
  const int wr = wid >> 1, wc = wid & 1;
  const int lr = lane & 15, lg = lane >> 4;

  f32x4 acc[4][4];
#pragma unroll
  for (int i = 0; i < 4; ++i)
#pragma unroll
    for (int j = 0; j < 4; ++j) acc[i][j] = {0.f, 0.f, 0.f, 0.f};

  for (int k0 = 0; k0 < K; k0 += 64) {
#pragma unroll
    for (int c = 0; c < 4; ++c) {
      int slot = tid + 256 * c;
      int r = slot >> 3;
      int cb = ((slot & 7) << 4) ^ ((r & 7) << 4);  // pre-swizzled src byte col
      int ldsoff = tid * 8 + c * 2048;              // ushort units (linear dest)
      gload_lds16(Ahi + (size_t)(m0 + r) * K + k0 + (cb >> 1), As + ldsoff);
      gload_lds16(Bhi + (size_t)(n0 + r) * K + k0 + (cb >> 1), Bs + ldsoff);
      if constexpr (SPLIT) {
        gload_lds16(Alo + (size_t)(m0 + r) * K + k0 + (cb >> 1), Als + ldsoff);
        gload_lds16(Blo + (size_t)(n0 + r) * K + k0 + (cb >> 1), Bls + ldsoff);
      }
    }
    __syncthreads();
#pragma unroll
    for (int kc = 0; kc < 2; ++kc) {
      short8 af[4], bf[4], afl[4], bfl[4];
#pragma unroll
      for (int mi = 0; mi < 4; ++mi) {
        int r = wr * 64 + mi * 16 + lr;
        int cb = (kc * 64 + lg * 16) ^ ((r & 7) << 4);
        af[mi] = *(const short8*)(As + r * 64 + (cb >> 1));
        if constexpr (SPLIT)
          afl[mi] = *(const short8*)(Als + r * 64 + (cb >> 1));
      }
#pragma unroll
      for (int ni = 0; ni < 4; ++ni) {
        int r = wc * 64 + ni * 16 + lr;
        int cb = (kc * 64 + lg * 16) ^ ((r & 7) << 4);
        bf[ni] = *(const short8*)(Bs + r * 64 + (cb >> 1));
        if constexpr (SPLIT)
          bfl[ni] = *(const short8*)(Bls + r * 64 + (cb >> 1));
      }
#pragma unroll
      for (int mi = 0; mi < 4; ++mi)
#pragma unroll
        for (int ni = 0; ni < 4; ++ni) {
          acc[mi][ni] = __builtin_amdgcn_mfma_f32_16x16x32_bf16(
              af[mi], bf[ni], acc[mi][ni], 0, 0, 0);
          if constexpr (SPLIT) {
            acc[mi][ni] = __builtin_amdgcn_mfma_f32_16x16x32_bf16(
                af[mi], bfl[ni], acc[mi][ni], 0, 0, 0);
            acc[mi][ni] = __builtin_amdgcn_mfma_f32_16x16x32_bf16(
                afl[mi], bf[ni], acc[mi][ni], 0, 0, 0);
          }
        }
    }
    __syncthreads();
  }
  // epilogue — C/D layout: col = lane&15, row = (lane>>4)*4 + reg
#pragma unroll
  for (int mi = 0; mi < 4; ++mi) {
#pragma unroll
    for (int ni = 0; ni < 4; ++ni) {
      int n = n0 + wc * 64 + ni * 16 + lr;
      float bs = bias[n];
#pragma unroll
      for (int rr = 0; rr < 4; ++rr) {
        int m = m0 + wr * 64 + mi * 16 + lg * 4 + rr;
        float v = acc[mi][ni][rr] + bs;
        if constexpr (MODE == 0) {
          int pair = ((n >> 6) << 1) + (m >> 11);
          size_t ad = (size_t)pair * 131072 + (size_t)(m & 2047) * 64 + (n & 63);
          unsigned short h = f2bf(v);
          ((unsigned short*)out0)[ad] = h;
          out1[ad] = f2bf(v - bf2f(h));
        } else if constexpr (MODE == 1) {
          int pair = ((n >> 6) << 1) + (m >> 11);
          size_t ad = (size_t)pair * 131072 + (size_t)(n & 63) * 2048 + (m & 2047);
          ((unsigned short*)out0)[ad] = f2bf(v);
        } else if constexpr (MODE == 2) {
          size_t ad = (size_t)m * N + n;
          ((float*)out0)[ad] = v + resid[ad];
        } else {
          size_t ad = (size_t)m * N + n;
          ((unsigned short*)out0)[ad] = f2bf(fmaxf(v, 0.f));
        }
      }
    }
  }
}

// ---------------------------------------------------------------------------
// Attention, quirk-faithful: scores = K·Q^T (no 1/sqrt(d)), softmax over t
// (query axis), o[s] = sum_t att[s,t] v[t].  Flash over t with MFMA.
// Q,K stored [pair][s][64] bf16 hi(+lo); V stored transposed [pair][64][2048].
// Block = 4 waves; wave owns 16 s-rows; t-tiles of 64 (4 sub-tiles of 16).
// QK^T in split-bf16 (3 MFMAs) for fp32-accurate logits.
// ---------------------------------------------------------------------------
__global__ __launch_bounds__(256) void attn_mfma(
    const unsigned short* __restrict__ Qhi, const unsigned short* __restrict__ Qlo,
    const unsigned short* __restrict__ Khi, const unsigned short* __restrict__ Klo,
    const unsigned short* __restrict__ Vt, unsigned short* __restrict__ O) {
  __shared__ unsigned short pl[4][16][72];  // per-wave P tile, 16B-aligned rows
  const int pair = blockIdx.x >> 5, stile = blockIdx.x & 31;
  const int tid = threadIdx.x, lane = tid & 63, wid = tid >> 6;
  const int lr = lane & 15, lg = lane >> 4;
  const size_t pbase = (size_t)pair * 131072;

  short8 ka[2], kal[2];  // K rows as A-frags (row = lr), split hi/lo
  {
    int s = stile * 64 + wid * 16 + lr;
    const unsigned short* kp = Khi + pbase + (size_t)s * 64;
    const unsigned short* kpl = Klo + pbase + (size_t)s * 64;
#pragma unroll
    for (int c = 0; c < 2; ++c) {
      ka[c] = *(const short8*)(kp + c * 32 + lg * 8);
      kal[c] = *(const short8*)(kpl + c * 32 + lg * 8);
    }
  }
  f32x4 oa[4];
#pragma unroll
  for (int i = 0; i < 4; ++i) oa[i] = {0.f, 0.f, 0.f, 0.f};
  float mrun[4], lrun[4];
#pragma unroll
  for (int r = 0; r < 4; ++r) {
    mrun[r] = -3e38f;
    lrun[r] = 0.f;
  }

  for (int t0 = 0; t0 < S_DIM; t0 += 64) {
    f32x4 sacc[4];
#pragma unroll
    for (int j = 0; j < 4; ++j) {
      sacc[j] = {0.f, 0.f, 0.f, 0.f};
      int t = t0 + j * 16 + lr;
      const unsigned short* qp = Qhi + pbase + (size_t)t * 64;
      const unsigned short* qpl = Qlo + pbase + (size_t)t * 64;
#pragma unroll
      for (int c = 0; c < 2; ++c) {
        short8 qb = *(const short8*)(qp + c * 32 + lg * 8);
        short8 qbl = *(const short8*)(qpl + c * 32 + lg * 8);
        sacc[j] = __builtin_amdgcn_mfma_f32_16x16x32_bf16(ka[c], qb, sacc[j], 0, 0, 0);
        sacc[j] = __builtin_amdgcn_mfma_f32_16x16x32_bf16(ka[c], qbl, sacc[j], 0, 0, 0);
        sacc[j] = __builtin_amdgcn_mfma_f32_16x16x32_bf16(kal[c], qb, sacc[j], 0, 0, 0);
      }
    }
    // online softmax over t; S rows s=(lg*4+r), cols t=(16j+lr).
    float tm[4];
#pragma unroll
    for (int r = 0; r < 4; ++r) {
      float m0v = fmaxf(fmaxf(sacc[0][r], sacc[1][r]),
                        fmaxf(sacc[2][r], sacc[3][r]));
#pragma unroll
      for (int w = 1; w < 16; w <<= 1) m0v = fmaxf(m0v, __shfl_xor(m0v, w));
      tm[r] = m0v;
    }
    float p[4][4], scale[4];
#pragma unroll
    for (int r = 0; r < 4; ++r) {
      float mn = fmaxf(mrun[r], tm[r]);
      scale[r] = __expf(mrun[r] - mn);
      mrun[r] = mn;
      float sm = 0.f;
#pragma unroll
      for (int j = 0; j < 4; ++j) {
        p[j][r] = __expf(sacc[j][r] - mn);
        sm += p[j][r];
      }
#pragma unroll
      for (int w = 1; w < 16; w <<= 1) sm += __shfl_xor(sm, w);
      lrun[r] = lrun[r] * scale[r] + sm;
    }
#pragma unroll
    for (int dj = 0; dj < 4; ++dj) {
      f32x4 t = oa[dj];
      t[0] *= scale[0]; t[1] *= scale[1]; t[2] *= scale[2]; t[3] *= scale[3];
      oa[dj] = t;
    }
    __syncthreads();  // previous-iter pa reads done before overwrite
#pragma unroll
    for (int j = 0; j < 4; ++j)
#pragma unroll
      for (int r = 0; r < 4; ++r)
        pl[wid][lg * 4 + r][j * 16 + lr] = f2bf(p[j][r]);
    __syncthreads();
    // PV: O[s][d] += P[s][t] V[t][d];  A=P rows (lr), B=V cols via Vt rows.
#pragma unroll
    for (int c = 0; c < 2; ++c) {
      short8 pa = *(const short8*)(&pl[wid][lr][0] + c * 32 + lg * 8);
#pragma unroll
      for (int dj = 0; dj < 4; ++dj) {
        int d = dj * 16 + lr;
        short8 vb = *(const short8*)(Vt + pbase + (size_t)d * 2048 + t0 +
                                     c * 32 + lg * 8);
        oa[dj] = __builtin_amdgcn_mfma_f32_16x16x32_bf16(pa, vb, oa[dj], 0, 0, 0);
      }
    }
  }
  // write O bf16 [b*2048+s][h*64+d]
  const int b = pair & 1, h = pair >> 1;
#pragma unroll
  for (int r = 0; r < 4; ++r) {
    int s = stile * 64 + wid * 16 + lg * 4 + r;
    float inv = 1.f / lrun[r];
    size_t rowb = (size_t)(b * 2048 + s) * 1024 + h * 64;
#pragma unroll
    for (int dj = 0; dj < 4; ++dj) O[rowb + dj * 16 + lr] = f2bf(oa[dj][r] * inv);
  }
}

// ---------------------------------------------------------------------------
extern "C" void kernel_launch(void* const* d_in, const int* in_sizes, int n_in,
                              void* d_out, int out_size, void* d_ws,
                              size_t ws_size, hipStream_t stream) {
  const float* x = (const float*)d_in[0];
  const float* Wq = (const float*)d_in[1];
  const float* bq = (const float*)d_in[2];
  const float* Wk = (const float*)d_in[3];
  const float* bk = (const float*)d_in[4];
  const float* Wv = (const float*)d_in[5];
  const float* bv = (const float*)d_in[6];
  const float* Wo = (const float*)d_in[7];
  const float* bo = (const float*)d_in[8];
  const float* ln1_g = (const float*)d_in[9];
  const float* ln1_b = (const float*)d_in[10];
  const float* ln2_g = (const float*)d_in[11];
  const float* ln2_b = (const float*)d_in[12];
  const float* W1 = (const float*)d_in[13];
  const float* b1 = (const float*)d_in[14];
  const float* W2 = (const float*)d_in[15];
  const float* b2 = (const float*)d_in[16];

  char* w = (char*)d_ws;
  const size_t MB = 1024 * 1024;
  unsigned short* WqTh = (unsigned short*)(w + 0 * MB);   // [1024][1024]
  unsigned short* WqTl = (unsigned short*)(w + 2 * MB);
  unsigned short* WkTh = (unsigned short*)(w + 4 * MB);
  unsigned short* WkTl = (unsigned short*)(w + 6 * MB);
  unsigned short* WvTh = (unsigned short*)(w + 8 * MB);
  unsigned short* WoTh = (unsigned short*)(w + 10 * MB);
  unsigned short* W1Th = (unsigned short*)(w + 12 * MB);  // [4096][1024]
  unsigned short* W2Th = (unsigned short*)(w + 20 * MB);  // [1024][4096]
  unsigned short* h_hi = (unsigned short*)(w + 28 * MB);  // [4096][1024]
  unsigned short* h_lo = (unsigned short*)(w + 36 * MB);
  unsigned short* Qhi = (unsigned short*)(w + 44 * MB);   // [32][2048][64]
  unsigned short* Qlo = (unsigned short*)(w + 52 * MB);
  unsigned short* Khi = (unsigned short*)(w + 60 * MB);
  unsigned short* Klo = (unsigned short*)(w + 68 * MB);
  unsigned short* Vt = (unsigned short*)(w + 76 * MB);    // [32][64][2048]
  unsigned short* Obuf = (unsigned short*)(w + 84 * MB);  // [4096][1024]
  float* x2 = (float*)(w + 44 * MB);                      // aliases Q (dead)
  unsigned short* m1 = (unsigned short*)(w + 60 * MB);    // aliases K/V/O (dead)

  const dim3 blk(256);

  transpose_w<true, true><<<dim3(32, 32), blk, 0, stream>>>(Wq, WqTh, WqTl, 1024, 1024);
  transpose_w<true, true><<<dim3(32, 32), blk, 0, stream>>>(Wk, WkTh, WkTl, 1024, 1024);
  transpose_w<true, false><<<dim3(32, 32), blk, 0, stream>>>(Wv, WvTh, nullptr, 1024, 1024);
  transpose_w<false, false><<<dim3(32, 32), blk, 0, stream>>>(Wo, WoTh, nullptr, 1024, 1024);
  transpose_w<false, false><<<dim3(128, 32), blk, 0, stream>>>(W1, W1Th, nullptr, 1024, 4096);
  transpose_w<false, false><<<dim3(32, 128), blk, 0, stream>>>(W2, W2Th, nullptr, 4096, 1024);

  ln_kernel<true><<<M_DIM, blk, 0, stream>>>(x, ln1_g, ln1_b, h_hi, h_lo);

  mfma_gemm<0, true><<<dim3(8, 32), blk, 65536, stream>>>(
      h_hi, h_lo, WqTh, WqTl, bq, nullptr, Qhi, Qlo, M_DIM, 1024, 1024);
  mfma_gemm<0, true><<<dim3(8, 32), blk, 65536, stream>>>(
      h_hi, h_lo, WkTh, WkTl, bk, nullptr, Khi, Klo, M_DIM, 1024, 1024);
  mfma_gemm<1, false><<<dim3(8, 32), blk, 32768, stream>>>(
      h_hi, nullptr, WvTh, nullptr, bv, nullptr, Vt, nullptr, M_DIM, 1024, 1024);

  attn_mfma<<<1024, blk, 0, stream>>>(Qhi, Qlo, Khi, Klo, Vt, Obuf);

  mfma_gemm<2, false><<<dim3(8, 32), blk, 32768, stream>>>(
      Obuf, nullptr, WoTh, nullptr, bo, x, x2, nullptr, M_DIM, 1024, 1024);

  ln_kernel<false><<<M_DIM, blk, 0, stream>>>(x2, ln2_g, ln2_b, h_hi, nullptr);

  mfma_gemm<3, false><<<dim3(32, 32), blk, 32768, stream>>>(
      h_hi, nullptr, W1Th, nullptr, b1, nullptr, m1, nullptr, M_DIM, 4096, 1024);
  mfma_gemm<2, false><<<dim3(8, 32), blk, 32768, stream>>>(
      m1, nullptr, W2Th, nullptr, b2, x2, (float*)d_out, nullptr, M_DIM, 1024, 4096);
}

// Round 3
// 421.309 us; speedup vs baseline: 9.0511x; 1.7413x over previous
//
#include <hip/hip_runtime.h>
#include <cstdint>
#include <cstddef>

typedef __attribute__((ext_vector_type(8))) short short8;
typedef __attribute__((ext_vector_type(4))) float f32x4;
typedef __attribute__((ext_vector_type(4))) unsigned short ushort4v;

#define E_DIM 1024
#define D_DIM 64
#define H_DIM 16
#define F_DIM 4096
#define B_DIM 2
#define S_DIM 2048
#define M_DIM 4096
#define LN_EPS 1e-5f

__device__ __forceinline__ float bf2f(unsigned short u) {
  union { unsigned int i; float f; } v;
  v.i = ((unsigned int)u) << 16;
  return v.f;
}
__device__ __forceinline__ unsigned short f2bf(float f) {
  union { float f; unsigned int i; } v;
  v.f = f;
  unsigned int r = v.i + 0x7FFFu + ((v.i >> 16) & 1u);
  return (unsigned short)(r >> 16);
}

__device__ __forceinline__ void gload_lds16(const unsigned short* src,
                                            unsigned short* dst) {
  __builtin_amdgcn_global_load_lds(
      (const __attribute__((address_space(1))) void*)src,
      (__attribute__((address_space(3))) void*)dst, 16, 0, 0);
}

// ---------------------------------------------------------------------------
// Weight prep: transpose fp32 [R][C] -> bf16 [C][R].
// QKV=true: input is [H][E][D], logical (r=e, c=h*64+d).
// ---------------------------------------------------------------------------
template <bool QKV>
__global__ __launch_bounds__(256) void transpose_w(
    const float* __restrict__ in, unsigned short* __restrict__ ohi, int R,
    int C) {
  __shared__ float t[32][33];
  const int c0 = blockIdx.x * 32, r0 = blockIdx.y * 32;
  const int tid = threadIdx.x;
  {
    const int rr = tid >> 3, c4 = (tid & 7) * 4;
    size_t addr;
    if (QKV)
      addr = (size_t)(c0 >> 6) * 65536 + (size_t)(r0 + rr) * 64 +
             ((c0 & 63) + c4);
    else
      addr = (size_t)(r0 + rr) * C + (c0 + c4);
    float4 v = *(const float4*)(in + addr);
    t[rr][c4 + 0] = v.x;
    t[rr][c4 + 1] = v.y;
    t[rr][c4 + 2] = v.z;
    t[rr][c4 + 3] = v.w;
  }
  __syncthreads();
  {
    const int cc = tid >> 3, k4 = (tid & 7) * 4;
    ushort4v hi;
    hi.x = f2bf(t[k4 + 0][cc]);
    hi.y = f2bf(t[k4 + 1][cc]);
    hi.z = f2bf(t[k4 + 2][cc]);
    hi.w = f2bf(t[k4 + 3][cc]);
    *(ushort4v*)(ohi + (size_t)(c0 + cc) * R + (r0 + k4)) = hi;
  }
}

// ---------------------------------------------------------------------------
// LayerNorm fp32 in -> bf16 out
// ---------------------------------------------------------------------------
__global__ __launch_bounds__(256) void ln_kernel(const float* __restrict__ x,
                                                 const float* __restrict__ g,
                                                 const float* __restrict__ b,
                                                 unsigned short* __restrict__ o) {
  const int row = blockIdx.x;
  const float* xp = x + (size_t)row * E_DIM;
  const int t4 = threadIdx.x * 4;
  float4 xv = *(const float4*)(xp + t4);
  float s = xv.x + xv.y + xv.z + xv.w;
  float ss = xv.x * xv.x + xv.y * xv.y + xv.z * xv.z + xv.w * xv.w;
#pragma unroll
  for (int off = 32; off > 0; off >>= 1) {
    s += __shfl_down(s, off);
    ss += __shfl_down(ss, off);
  }
  __shared__ float red[8];
  const int wid = threadIdx.x >> 6;
  if ((threadIdx.x & 63) == 0) {
    red[wid] = s;
    red[4 + wid] = ss;
  }
  __syncthreads();
  if (threadIdx.x == 0) {
    float S = red[0] + red[1] + red[2] + red[3];
    float SS = red[4] + red[5] + red[6] + red[7];
    float mean = S * (1.0f / E_DIM);
    float var = SS * (1.0f / E_DIM) - mean * mean;
    red[0] = mean;
    red[1] = rsqrtf(var + LN_EPS);
  }
  __syncthreads();
  const float mean = red[0], rstd = red[1];
  float4 gv = *(const float4*)(g + t4);
  float4 bv = *(const float4*)(b + t4);
  ushort4v hi;
  hi.x = f2bf((xv.x - mean) * rstd * gv.x + bv.x);
  hi.y = f2bf((xv.y - mean) * rstd * gv.y + bv.y);
  hi.z = f2bf((xv.z - mean) * rstd * gv.z + bv.z);
  hi.w = f2bf((xv.w - mean) * rstd * gv.w + bv.w);
  *(ushort4v*)(o + (size_t)row * E_DIM + t4) = hi;
}

// ---------------------------------------------------------------------------
// MFMA GEMM: C[M,N] = A[M,K] * B^T (B stored [N][K], bf16).
// 128x128 tile, BK=64, 4 waves, global_load_lds w16, XOR-swizzled LDS.
// MODE 0: fused QKV: n<1024 -> Q[pair][s][d]; <2048 -> K same; else Vt[pair][d][s]
// MODE 2: fp32 out = acc + bias[n] + resid[m][n]       (Wo)
// MODE 3: bf16 out = relu(acc + bias[n])               (W1)
// MODE 4: split-K (gridDim.z=4): atomicAdd fp32 out += acc  (W2)
// ---------------------------------------------------------------------------
template <int MODE>
__global__ __launch_bounds__(256) void mfma_gemm(
    const unsigned short* __restrict__ A, const unsigned short* __restrict__ B,
    const float* __restrict__ bias, const float* __restrict__ bias2,
    const float* __restrict__ bias3, const float* __restrict__ resid,
    void* __restrict__ out0, void* __restrict__ out1, void* __restrict__ out2,
    int M, int N, int K) {
  __shared__ unsigned short As[8192];
  __shared__ unsigned short Bs[8192];
  const int tid = threadIdx.x;
  const int m0 = blockIdx.y * 128, n0 = blockIdx.x * 128;
  const int lane = tid & 63, wid = tid >> 6;
  const int wr = wid >> 1, wc = wid & 1;
  const int lr = lane & 15, lg = lane >> 4;

  f32x4 acc[4][4];
#pragma unroll
  for (int i = 0; i < 4; ++i)
#pragma unroll
    for (int j = 0; j < 4; ++j) acc[i][j] = {0.f, 0.f, 0.f, 0.f};

  const int kbeg = (MODE == 4) ? blockIdx.z * 1024 : 0;
  const int kend = (MODE == 4) ? kbeg + 1024 : K;

  for (int k0 = kbeg; k0 < kend; k0 += 64) {
#pragma unroll
    for (int c = 0; c < 4; ++c) {
      int slot = tid + 256 * c;
      int r = slot >> 3;
      int cb = ((slot & 7) << 4) ^ ((r & 7) << 4);
      int ldsoff = tid * 8 + c * 2048;
      gload_lds16(A + (size_t)(m0 + r) * K + k0 + (cb >> 1), As + ldsoff);
      gload_lds16(B + (size_t)(n0 + r) * K + k0 + (cb >> 1), Bs + ldsoff);
    }
    __syncthreads();
#pragma unroll
    for (int kc = 0; kc < 2; ++kc) {
      short8 af[4], bf[4];
#pragma unroll
      for (int mi = 0; mi < 4; ++mi) {
        int r = wr * 64 + mi * 16 + lr;
        int cb = (kc * 64 + lg * 16) ^ ((r & 7) << 4);
        af[mi] = *(const short8*)(As + r * 64 + (cb >> 1));
      }
#pragma unroll
      for (int ni = 0; ni < 4; ++ni) {
        int r = wc * 64 + ni * 16 + lr;
        int cb = (kc * 64 + lg * 16) ^ ((r & 7) << 4);
        bf[ni] = *(const short8*)(Bs + r * 64 + (cb >> 1));
      }
#pragma unroll
      for (int mi = 0; mi < 4; ++mi)
#pragma unroll
        for (int ni = 0; ni < 4; ++ni)
          acc[mi][ni] = __builtin_amdgcn_mfma_f32_16x16x32_bf16(
              af[mi], bf[ni], acc[mi][ni], 0, 0, 0);
    }
    __syncthreads();
  }
  // epilogue — C/D layout: col = lane&15, row = (lane>>4)*4 + reg
#pragma unroll
  for (int mi = 0; mi < 4; ++mi) {
#pragma unroll
    for (int ni = 0; ni < 4; ++ni) {
      int n = n0 + wc * 64 + ni * 16 + lr;
#pragma unroll
      for (int rr = 0; rr < 4; ++rr) {
        int m = m0 + wr * 64 + mi * 16 + lg * 4 + rr;
        float v = acc[mi][ni][rr];
        if constexpr (MODE == 0) {
          int seg = n >> 10, nn = n & 1023;
          const float* bp = seg == 0 ? bias : seg == 1 ? bias2 : bias3;
          v += bp[nn];
          int hh = nn >> 6, d = nn & 63, bb = m >> 11, srow = m & 2047;
          size_t pb = (size_t)(hh * 2 + bb) * 131072;
          if (seg == 0)
            ((unsigned short*)out0)[pb + (size_t)srow * 64 + d] = f2bf(v);
          else if (seg == 1)
            ((unsigned short*)out1)[pb + (size_t)srow * 64 + d] = f2bf(v);
          else
            ((unsigned short*)out2)[pb + (size_t)d * 2048 + srow] = f2bf(v);
        } else if constexpr (MODE == 2) {
          size_t ad = (size_t)m * N + n;
          ((float*)out0)[ad] = v + bias[n] + resid[ad];
        } else if constexpr (MODE == 3) {
          ((unsigned short*)out0)[(size_t)m * N + n] = f2bf(fmaxf(v + bias[n], 0.f));
        } else {
          unsafeAtomicAdd((float*)out0 + (size_t)m * N + n, v);
        }
      }
    }
  }
}

// ---------------------------------------------------------------------------
// Attention (quirk-faithful): scores = K·Q^T unscaled, softmax over query t.
// Orientation: S^T = Q·K^T so each lane owns ONE s-column (softmax = 2 shfl),
// and P^T B-frags for PV come from a pure lane-group shuffle (no LDS P).
// Q,K: [pair][2048][64] bf16; Vt: [pair][64][2048] bf16. O: [4096][1024] bf16.
// Block = 4 waves x 16 s-cols = 64 s. Q/V t-tiles (64) dbuf in LDS.
// ---------------------------------------------------------------------------
__global__ __launch_bounds__(256, 4) void attn_mfma(
    const unsigned short* __restrict__ Q, const unsigned short* __restrict__ K,
    const unsigned short* __restrict__ Vt, unsigned short* __restrict__ O) {
  __shared__ unsigned short Qs[2][4096];
  __shared__ unsigned short Vs[2][4096];
  const int bid = blockIdx.x;
  const int wg = (bid & 7) * 128 + (bid >> 3);  // XCD-chunked swizzle (1024%8==0)
  const int pair = wg >> 5, stile = wg & 31;
  const int tid = threadIdx.x, lane = tid & 63, wid = tid >> 6;
  const int lr = lane & 15, lg = lane >> 4;
  const size_t pbase = (size_t)pair * 131072;

  const int s_own = stile * 64 + wid * 16 + lr;
  short8 kb[2];  // B-frag: col s = lr-owned, k = d
#pragma unroll
  for (int c = 0; c < 2; ++c)
    kb[c] = *(const short8*)(K + pbase + (size_t)s_own * 64 + c * 32 + lg * 8);

  f32x4 oa[4];
#pragma unroll
  for (int i = 0; i < 4; ++i) oa[i] = {0.f, 0.f, 0.f, 0.f};
  float mrun = -3e38f, lrun = 0.f;

  auto stage = [&](int buf, int t0) {
#pragma unroll
    for (int c = 0; c < 2; ++c) {
      int slot = tid + 256 * c;
      int r = slot >> 3;
      int cb = ((slot & 7) << 4) ^ ((r & 7) << 4);
      gload_lds16(Q + pbase + (size_t)(t0 + r) * 64 + (cb >> 1),
                  &Qs[buf][slot * 8]);
      gload_lds16(Vt + pbase + (size_t)r * 2048 + t0 + (cb >> 1),
                  &Vs[buf][slot * 8]);
    }
  };

  stage(0, 0);
  __syncthreads();

  for (int it = 0; it < 32; ++it) {
    const int cur = it & 1;
    if (it < 31) stage(cur ^ 1, (it + 1) * 64);

    // S^T tile: sacc[j][r] = S[t = j*16 + lg*4 + r][s = lr]
    f32x4 sacc[4];
#pragma unroll
    for (int j = 0; j < 4; ++j) {
      sacc[j] = {0.f, 0.f, 0.f, 0.f};
#pragma unroll
      for (int c = 0; c < 2; ++c) {
        int row = j * 16 + lr;
        int cb = (c * 64 + lg * 16) ^ ((row & 7) << 4);
        short8 aq = *(const short8*)(&Qs[cur][row * 64 + (cb >> 1)]);
        sacc[j] = __builtin_amdgcn_mfma_f32_16x16x32_bf16(aq, kb[c], sacc[j], 0, 0, 0);
      }
    }
    // softmax over t for this lane's s-col
    float mj0 = fmaxf(fmaxf(sacc[0][0], sacc[0][1]), fmaxf(sacc[0][2], sacc[0][3]));
    float mj1 = fmaxf(fmaxf(sacc[1][0], sacc[1][1]), fmaxf(sacc[1][2], sacc[1][3]));
    float mj2 = fmaxf(fmaxf(sacc[2][0], sacc[2][1]), fmaxf(sacc[2][2], sacc[2][3]));
    float mj3 = fmaxf(fmaxf(sacc[3][0], sacc[3][1]), fmaxf(sacc[3][2], sacc[3][3]));
    float tm = fmaxf(fmaxf(mj0, mj1), fmaxf(mj2, mj3));
    tm = fmaxf(tm, __shfl_xor(tm, 16));
    tm = fmaxf(tm, __shfl_xor(tm, 32));
    float mnew = fmaxf(mrun, tm);
    float scale = __expf(mrun - mnew);
    mrun = mnew;
    float p[4][4];
#pragma unroll
    for (int j = 0; j < 4; ++j)
#pragma unroll
      for (int r = 0; r < 4; ++r) p[j][r] = __expf(sacc[j][r] - mnew);
    float lsum = ((p[0][0] + p[0][1]) + (p[0][2] + p[0][3])) +
                 ((p[1][0] + p[1][1]) + (p[1][2] + p[1][3])) +
                 ((p[2][0] + p[2][1]) + (p[2][2] + p[2][3])) +
                 ((p[3][0] + p[3][1]) + (p[3][2] + p[3][3]));
    lsum += __shfl_xor(lsum, 16);
    lsum += __shfl_xor(lsum, 32);
    lrun = lrun * scale + lsum;
#pragma unroll
    for (int di = 0; di < 4; ++di) {
      f32x4 t = oa[di];
      t[0] *= scale; t[1] *= scale; t[2] *= scale; t[3] *= scale;
      oa[di] = t;
    }
    // pack P rows (bf16 pairs) for shuffle-transpose
    unsigned int pw[4][2];
#pragma unroll
    for (int j = 0; j < 4; ++j) {
      pw[j][0] = (unsigned)f2bf(p[j][0]) | ((unsigned)f2bf(p[j][1]) << 16);
      pw[j][1] = (unsigned)f2bf(p[j][2]) | ((unsigned)f2bf(p[j][3]) << 16);
    }
    // PV: O^T[d][s] += Vt[d][t] * P^T[t][s]
#pragma unroll
    for (int kc = 0; kc < 2; ++kc) {
      unsigned int bw[4];
#pragma unroll
      for (int mm = 0; mm < 4; ++mm) {
        int src = ((lg & 1) * 2 + (mm >> 1)) * 16 + lr;
        int lo = __shfl((int)pw[2 * kc][mm & 1], src, 64);
        int hi = __shfl((int)pw[2 * kc + 1][mm & 1], src, 64);
        bw[mm] = (lg & 2) ? (unsigned)hi : (unsigned)lo;
      }
      union { unsigned int u[4]; short8 s8; } pb;
      pb.u[0] = bw[0]; pb.u[1] = bw[1]; pb.u[2] = bw[2]; pb.u[3] = bw[3];
#pragma unroll
      for (int di = 0; di < 4; ++di) {
        int row = di * 16 + lr;
        int cb = (kc * 64 + lg * 16) ^ ((row & 7) << 4);
        short8 vf = *(const short8*)(&Vs[cur][row * 64 + (cb >> 1)]);
        oa[di] = __builtin_amdgcn_mfma_f32_16x16x32_bf16(vf, pb.s8, oa[di], 0, 0, 0);
      }
    }
    __syncthreads();
  }

  const float inv = 1.f / lrun;
  const int b = pair & 1, h = pair >> 1;
  unsigned short* op = O + ((size_t)(b * 2048 + s_own)) * 1024 + h * 64;
#pragma unroll
  for (int di = 0; di < 4; ++di) {
    unsigned int w0 = (unsigned)f2bf(oa[di][0] * inv) |
                      ((unsigned)f2bf(oa[di][1] * inv) << 16);
    unsigned int w1 = (unsigned)f2bf(oa[di][2] * inv) |
                      ((unsigned)f2bf(oa[di][3] * inv) << 16);
    *(unsigned int*)(op + di * 16 + lg * 4) = w0;
    *(unsigned int*)(op + di * 16 + lg * 4 + 2) = w1;
  }
}

// ---------------------------------------------------------------------------
// init d_out = x2 + b2 (before W2 split-K atomics)
// ---------------------------------------------------------------------------
__global__ __launch_bounds__(256) void init_out(const float* __restrict__ x2,
                                                const float* __restrict__ b2,
                                                float* __restrict__ out) {
  int i = blockIdx.x * 256 + threadIdx.x;  // float4 index; row = 256 float4
  float4 v = ((const float4*)x2)[i];
  float4 bb = ((const float4*)b2)[i & 255];
  v.x += bb.x; v.y += bb.y; v.z += bb.z; v.w += bb.w;
  ((float4*)out)[i] = v;
}

// ---------------------------------------------------------------------------
extern "C" void kernel_launch(void* const* d_in, const int* in_sizes, int n_in,
                              void* d_out, int out_size, void* d_ws,
                              size_t ws_size, hipStream_t stream) {
  const float* x = (const float*)d_in[0];
  const float* Wq = (const float*)d_in[1];
  const float* bq = (const float*)d_in[2];
  const float* Wk = (const float*)d_in[3];
  const float* bk = (const float*)d_in[4];
  const float* Wv = (const float*)d_in[5];
  const float* bv = (const float*)d_in[6];
  const float* Wo = (const float*)d_in[7];
  const float* bo = (const float*)d_in[8];
  const float* ln1_g = (const float*)d_in[9];
  const float* ln1_b = (const float*)d_in[10];
  const float* ln2_g = (const float*)d_in[11];
  const float* ln2_b = (const float*)d_in[12];
  const float* W1 = (const float*)d_in[13];
  const float* b1 = (const float*)d_in[14];
  const float* W2 = (const float*)d_in[15];
  const float* b2 = (const float*)d_in[16];

  char* w = (char*)d_ws;
  const size_t MB = 1024 * 1024;
  unsigned short* WqkvT = (unsigned short*)(w + 0 * MB);  // [3072][1024]
  unsigned short* WoT = (unsigned short*)(w + 6 * MB);    // [1024][1024]
  unsigned short* W1T = (unsigned short*)(w + 8 * MB);    // [4096][1024]
  unsigned short* W2T = (unsigned short*)(w + 16 * MB);   // [1024][4096]
  unsigned short* h = (unsigned short*)(w + 24 * MB);     // [4096][1024]
  unsigned short* Qb = (unsigned short*)(w + 32 * MB);    // [32][2048][64]
  unsigned short* Kb = (unsigned short*)(w + 40 * MB);
  unsigned short* Vt = (unsigned short*)(w + 48 * MB);    // [32][64][2048]
  unsigned short* Obuf = (unsigned short*)(w + 56 * MB);  // [4096][1024]
  unsigned short* m1 = (unsigned short*)(w + 32 * MB);    // [4096][4096], aliases Q..O
  float* x2 = (float*)(w + 64 * MB);                      // [4096][1024] fp32

  const dim3 blk(256);

  transpose_w<true><<<dim3(32, 32), blk, 0, stream>>>(Wq, WqkvT, 1024, 1024);
  transpose_w<true><<<dim3(32, 32), blk, 0, stream>>>(Wk, WqkvT + 1048576, 1024, 1024);
  transpose_w<true><<<dim3(32, 32), blk, 0, stream>>>(Wv, WqkvT + 2097152, 1024, 1024);
  transpose_w<false><<<dim3(32, 32), blk, 0, stream>>>(Wo, WoT, 1024, 1024);
  transpose_w<false><<<dim3(128, 32), blk, 0, stream>>>(W1, W1T, 1024, 4096);
  transpose_w<false><<<dim3(32, 128), blk, 0, stream>>>(W2, W2T, 4096, 1024);

  ln_kernel<<<M_DIM, blk, 0, stream>>>(x, ln1_g, ln1_b, h);

  mfma_gemm<0><<<dim3(24, 32), blk, 0, stream>>>(h, WqkvT, bq, bk, bv, nullptr,
                                                 Qb, Kb, Vt, M_DIM, 3072, 1024);

  attn_mfma<<<1024, blk, 0, stream>>>(Qb, Kb, Vt, Obuf);

  mfma_gemm<2><<<dim3(8, 32), blk, 0, stream>>>(Obuf, WoT, bo, nullptr, nullptr,
                                                x, x2, nullptr, nullptr, M_DIM,
                                                1024, 1024);

  ln_kernel<<<M_DIM, blk, 0, stream>>>(x2, ln2_g, ln2_b, h);

  mfma_gemm<3><<<dim3(32, 32), blk, 0, stream>>>(h, W1T, b1, nullptr, nullptr,
                                                 nullptr, m1, nullptr, nullptr,
                                                 M_DIM, 4096, 1024);

  init_out<<<4096, blk, 0, stream>>>(x2, b2, (float*)d_out);

  mfma_gemm<4><<<dim3(8, 32, 4), blk, 0, stream>>>(
      m1, W2T, nullptr, nullptr, nullptr, nullptr, (float*)d_out, nullptr,
      nullptr, M_DIM, 1024, 4096);
}